// Round 10
// baseline (352.179 us; speedup 1.0000x reference)
//
#include <hip/hip_runtime.h>
#include <stdint.h>

// Problem constants
#define PP 8
#define FIN 1024
#define FOUT 1024
#define MROWS 8192
#define ROWSTRIDE 8192
#define OROWSTRIDE 8192
#define NKT 16                 // K-tiles of 64

typedef float fx4 __attribute__((ext_vector_type(4)));
typedef short sv8 __attribute__((ext_vector_type(8)));

union BCvt { sv8 s; __bf16 b[8]; };

__device__ __forceinline__ unsigned short bfbits(float f) {
    union { __bf16 b; unsigned short u; } c; c.b = (__bf16)f; return c.u;
}
__device__ __forceinline__ sv8 cvt8(fx4 lo, fx4 hi) {
    BCvt u;
#pragma unroll
    for (int i = 0; i < 4; ++i) { u.b[i] = (__bf16)lo[i]; u.b[i + 4] = (__bf16)hi[i]; }
    return u.s;
}

// ---------------------------------------------------------------------------
// Swizzled image format: byte = row*128 + ((kg*16) ^ ((row&7)<<4)), kg = k/8
// ---------------------------------------------------------------------------

// Prepass (verified r5-r9): W [P][K][N] fp32 -> Wt 16 KB tiles (p, nt128, kt)
__global__ __launch_bounds__(256) void wtrans(const float* __restrict__ w,
                                              unsigned short* __restrict__ wt) {
    __shared__ unsigned short L[64][132];
    const int bid = blockIdx.x;              // 1024
    const int p  = bid >> 7;
    const int nt = (bid >> 4) & 7;
    const int kt = bid & 15;
    const int k0 = kt * 64, n0 = nt * 128;
    const int t = threadIdx.x;

    const int nf = t & 31, kl = t >> 5;
#pragma unroll
    for (int rr = 0; rr < 8; ++rr) {
        const int k = rr * 8 + kl;
        fx4 v = *(const fx4*)(w + (size_t)p * (FIN*FOUT) + (size_t)(k0 + k) * FOUT + n0 + nf * 4);
        L[k][nf*4+0] = bfbits(v[0]); L[k][nf*4+1] = bfbits(v[1]);
        L[k][nf*4+2] = bfbits(v[2]); L[k][nf*4+3] = bfbits(v[3]);
    }
    __syncthreads();

    unsigned short* tile = wt + (size_t)bid * 8192;
    const int n = t & 127, khalf = t >> 7;
#pragma unroll
    for (int rr = 0; rr < 4; ++rr) {
        const int kg = khalf * 4 + rr;
        union { sv8 s; unsigned short us[8]; } u;
#pragma unroll
        for (int e = 0; e < 8; ++e) u.us[e] = L[kg * 8 + e][n];
        const int byte_ = n * 128 + ((kg * 16) ^ ((n & 7) << 4));
        *(sv8*)((char*)tile + byte_) = u.s;
    }
}

// ---------------------------------------------------------------------------
// Fused 128x128 GEMM, 2 blocks/CU. A reg-staged fp32->bf16 (1 tile ahead),
// B pure global_load_lds from Wt (1 tile ahead), coarse counted schedule.
// ---------------------------------------------------------------------------
#define MEMF asm volatile("" ::: "memory")

// A fp32 loads for tile kt -> rA (8 x dwordx4). thread: arow=tid>>1, akh=tid&1
#define LOADA(kt) do {                                                         \
    const float* s_ = aptr + (kt) * 64;                                        \
    _Pragma("unroll")                                                          \
    for (int j_ = 0; j_ < 8; ++j_) rA[j_] = *(const fx4*)(s_ + j_ * 4);        \
} while (0)

// cvt rA -> 4 x ds_write_b128 into swizzled 16 KB image
#define STOREA(As) do {                                                        \
    const int sw_ = (arow & 7) << 4;                                           \
    char* bp_ = (As) + arow * 128;                                             \
    _Pragma("unroll")                                                          \
    for (int j_ = 0; j_ < 4; ++j_) {                                           \
        const int kg_ = akh * 4 + j_;                                          \
        *(sv8*)(bp_ + ((kg_ * 16) ^ sw_)) = cvt8(rA[2*j_], rA[2*j_+1]);        \
    }                                                                          \
} while (0)

// B: 16 KB tile = 4 x global_load_lds (256 thr x 16 B)
#define GLB(kt, Bs) do {                                                       \
    const char* s_ = btile + (size_t)(kt) * 16384 + tid * 16;                  \
    char* d_ = (Bs) + tid * 16;                                                \
    _Pragma("unroll")                                                          \
    for (int c_ = 0; c_ < 4; ++c_)                                             \
        __builtin_amdgcn_global_load_lds(                                      \
            (const __attribute__((address_space(1))) void*)(s_ + c_ * 4096),   \
            (__attribute__((address_space(3))) void*)(d_ + c_ * 4096), 16, 0, 0); \
} while (0)

// frags: 8 x ds_read_b128 from 64 rows starting r0
#define RD8(base, r0, dst) do {                                                \
    _Pragma("unroll")                                                          \
    for (int fi_ = 0; fi_ < 4; ++fi_) {                                        \
        const int row_ = (r0) + fi_ * 16 + (lane & 15);                        \
        const char* bp_ = (base) + row_ * 128;                                 \
        const int sw_ = (row_ & 7) << 4;                                       \
        _Pragma("unroll")                                                      \
        for (int ks_ = 0; ks_ < 2; ++ks_)                                      \
            dst[fi_][ks_] = *(const sv8*)(bp_ + ((ks_ * 64 + (lane >> 4) * 16) ^ sw_)); \
    }                                                                          \
} while (0)

// 32 MFMA: 4x4 fragments x 2 k-slices
#define MFMAS do {                                                             \
    _Pragma("unroll")                                                          \
    for (int fi_ = 0; fi_ < 4; ++fi_)                                          \
        _Pragma("unroll")                                                      \
        for (int fj_ = 0; fj_ < 4; ++fj_)                                      \
            _Pragma("unroll")                                                  \
            for (int ks_ = 0; ks_ < 2; ++ks_)                                  \
                acc[fi_][fj_] = __builtin_amdgcn_mfma_f32_16x16x32_bf16(       \
                    af[fi_][ks_], bf[fj_][ks_], acc[fi_][fj_], 0, 0, 0);       \
} while (0)

// Ledger: entry = A(t+1) 8 outstanding (regs rA).
//  GLB +4 (B(t+1)); STOREA auto-waits vmcnt(4) (rA oldest; keeps B);
//  LOADA(t+2) +8; end vmcnt(8) retires B(t+1), leaves A(t+2). Invariant ok.
// ENDW: 2 = vmcnt(8), 1 = vmcnt(0) (t=14), 0 = none (t=15)
#define TILE(t, Ar, Br, As, Bs, STG, PREF, ENDW) do {                          \
    if (STG) GLB((t) + 1, Bs);                                                 \
    MEMF;                                                                      \
    if (STG) STOREA(As);                                                       \
    MEMF;                                                                      \
    if (PREF) LOADA((t) + 2);                                                  \
    MEMF;                                                                      \
    RD8((Ar) + wm * 8192, 0, af);                                              \
    RD8((Br) + wn * 8192, 0, bf);                                              \
    MFMAS;                                                                     \
    if ((ENDW) == 2) {                                                         \
        asm volatile("s_waitcnt vmcnt(8) lgkmcnt(0)" ::: "memory");            \
        __builtin_amdgcn_s_barrier(); MEMF;                                    \
    } else if ((ENDW) == 1) {                                                  \
        asm volatile("s_waitcnt vmcnt(0) lgkmcnt(0)" ::: "memory");            \
        __builtin_amdgcn_s_barrier(); MEMF;                                    \
    }                                                                          \
} while (0)

__global__ __launch_bounds__(256, 2)
void pd_gemm(const float* __restrict__ x, const unsigned short* __restrict__ wt,
             const float* __restrict__ bias, float* __restrict__ out) {
    __shared__ __align__(16) char A0[16384];
    __shared__ __align__(16) char A1[16384];
    __shared__ __align__(16) char B0[16384];
    __shared__ __align__(16) char B1[16384];   // 64 KB -> 2 blocks/CU

    const int tid = threadIdx.x;
    const int lane = tid & 63;
    const int wv = tid >> 6;            // 4 waves: 2(m) x 2(n); wave = 64x64
    const int wm = wv >> 1, wn = wv & 1;

    // 4096 blocks: p==XCD fastest, nt next (8 A-panel sharers same XCD), mt last
    const int bid = blockIdx.x;
    const int p   = bid & 7;
    const int q   = bid >> 3;
    const int nt  = q & 7;
    const int mt  = q >> 3;             // 0..63
    const int n0  = nt * 128;
    const int m0  = mt * 128;

    const int arow = tid >> 1, akh = tid & 1;   // A staging map
    const float* aptr = x + (size_t)(m0 + arow) * ROWSTRIDE + p * FIN + akh * 32;
    const char* btile = (const char*)(wt + (size_t)((p * 8 + nt) * 16) * 8192);

    fx4 acc[4][4];
#pragma unroll
    for (int i = 0; i < 4; ++i)
#pragma unroll
        for (int j = 0; j < 4; ++j) acc[i][j] = (fx4)0.0f;

    fx4 rA[8];
    sv8 af[4][2], bf[4][2];

    // Prologue: B(0)->B0 (4), A(0)->rA (8), stage A0 (drains all: prologue
    // only), A(1)->rA (8). Entry invariant: A(1) 8 outstanding; A0/B0 staged.
    GLB(0, B0);
    MEMF;
    LOADA(0);
    MEMF;
    STOREA(A0);
    MEMF;
    LOADA(1);
    asm volatile("s_waitcnt vmcnt(8) lgkmcnt(0)" ::: "memory");
    __builtin_amdgcn_s_barrier();
    MEMF;

#pragma unroll 1
    for (int tt = 0; tt < 7; ++tt) {
        const int t = 2 * tt;
        TILE(t,     A0, B0, A1, B1, 1, 1, 2);
        TILE(t + 1, A1, B1, A0, B0, 1, 1, 2);
    }
    TILE(14, A0, B0, A1, B1, 1, 0, 1);   // stage A(15),B(15); drain
    TILE(15, A1, B1, A0, B0, 0, 0, 0);

    // Epilogue: C/D map col = lane&15, row = (lane>>4)*4 + j (verified r1-r9)
    const float* bs = bias + p * FOUT;
#pragma unroll
    for (int fj = 0; fj < 4; ++fj) {
        const int col = n0 + wn * 64 + fj * 16 + (lane & 15);
        const float bv = bs[col];
#pragma unroll
        for (int fi = 0; fi < 4; ++fi) {
            const int row = m0 + wm * 64 + fi * 16 + (lane >> 4) * 4;
            float* o = out + (size_t)row * OROWSTRIDE + p * FOUT + col;
#pragma unroll
            for (int j = 0; j < 4; ++j)
                o[j * OROWSTRIDE] = acc[fi][fj][j] + bv;
        }
    }
}

// Fallback if d_ws too small: correct but slow (fp32 exact).
__global__ __launch_bounds__(256) void pd_naive(const float* __restrict__ x,
                                                const float* __restrict__ w,
                                                const float* __restrict__ bias,
                                                float* __restrict__ out) {
    const long long total = (long long)MROWS * PP * FOUT;
    for (long long idx = blockIdx.x * 256LL + threadIdx.x; idx < total;
         idx += (long long)gridDim.x * 256) {
        const int n = (int)(idx & 1023);
        const int p = (int)((idx >> 10) & 7);
        const long long m = idx >> 13;
        const float* xr = x + m * ROWSTRIDE + p * FIN;
        const float* wc = w + (size_t)p * (FIN*FOUT) + n;
        float s = bias[p * FOUT + n];
        for (int k = 0; k < FIN; ++k) s += xr[k] * wc[(size_t)k * FOUT];
        out[idx] = s;
    }
}

extern "C" void kernel_launch(void* const* d_in, const int* in_sizes, int n_in,
                              void* d_out, int out_size, void* d_ws, size_t ws_size,
                              hipStream_t stream) {
    const float* x    = (const float*)d_in[0];
    const float* w    = (const float*)d_in[1];
    const float* bias = (const float*)d_in[2];
    float* out = (float*)d_out;

    const size_t WT_BYTES = (size_t)PP * FIN * FOUT * 2;   // 16.8 MB
    if (ws_size >= WT_BYTES) {
        unsigned short* wt = (unsigned short*)d_ws;
        wtrans<<<dim3(1024), dim3(256), 0, stream>>>(w, wt);
        // 8 p x 8 nt x 64 mt = 4096 blocks of 256 threads
        pd_gemm<<<dim3(4096), dim3(256), 0, stream>>>(x, wt, bias, out);
    } else {
        pd_naive<<<dim3(2048), dim3(256), 0, stream>>>(x, w, bias, out);
    }
}

// Round 11
// 306.183 us; speedup vs baseline: 1.1502x; 1.1502x over previous
//
#include <hip/hip_runtime.h>
#include <stdint.h>

// Problem constants
#define PP 8
#define FIN 1024
#define FOUT 1024
#define MROWS 8192
#define ROWSTRIDE 8192
#define OROWSTRIDE 8192

typedef float fx4 __attribute__((ext_vector_type(4)));
typedef short sv8 __attribute__((ext_vector_type(8)));
typedef short sv4 __attribute__((ext_vector_type(4)));

union BCvt4 { sv4 s; __bf16 b[4]; };

__device__ __forceinline__ unsigned short bfbits(float f) {
    union { __bf16 b; unsigned short u; } c; c.b = (__bf16)f; return c.u;
}

// ---------------------------------------------------------------------------
// BK=32 tile images, plain row-major (NO swizzle):
//   A tile (p, mt256, kt32): [256 rows][32 k] bf16 = 16 KB
//   B tile (p, nt128, kt32): [128 rows][32 k] bf16 =  8 KB
// Frag reads are conflict-free: 64 lanes cover a contiguous 1 KB.
// ---------------------------------------------------------------------------

// Prepass 1: W [P][K][N] fp32 -> Wt. Block per (p, nt, kt64) -> two kt32 tiles.
__global__ __launch_bounds__(256) void wtrans(const float* __restrict__ w,
                                              unsigned short* __restrict__ wt) {
    __shared__ unsigned short L[64][132];
    const int bid = blockIdx.x;              // 8*8*16 = 1024
    const int p  = bid >> 7;
    const int nt = (bid >> 4) & 7;
    const int kt64 = bid & 15;
    const int k0 = kt64 * 64, n0 = nt * 128;
    const int t = threadIdx.x;

    const int nf = t & 31, kl = t >> 5;
#pragma unroll
    for (int rr = 0; rr < 8; ++rr) {
        const int k = rr * 8 + kl;
        fx4 v = *(const fx4*)(w + (size_t)p * (FIN*FOUT) + (size_t)(k0 + k) * FOUT + n0 + nf * 4);
        L[k][nf*4+0] = bfbits(v[0]); L[k][nf*4+1] = bfbits(v[1]);
        L[k][nf*4+2] = bfbits(v[2]); L[k][nf*4+3] = bfbits(v[3]);
    }
    __syncthreads();

    // two 8 KB tiles: [128 n][32 k] row-major
    const int n = t >> 1, half = t & 1;
    unsigned short* tile = wt + (size_t)((p * 8 + nt) * 32 + kt64 * 2 + half) * 4096;
#pragma unroll
    for (int g = 0; g < 4; ++g) {
        union { sv8 s; unsigned short us[8]; } u;
#pragma unroll
        for (int e = 0; e < 8; ++e) u.us[e] = L[half * 32 + g * 8 + e][n];
        *(sv8*)((char*)tile + n * 64 + g * 16) = u.s;
    }
}

// Prepass 2: x fp32 -> xt tiles [256][32] bf16. Wave-per-row, coalesced reads.
__global__ __launch_bounds__(256) void xcvt(const float* __restrict__ x,
                                            unsigned short* __restrict__ xt,
                                            int m_base, int MT) {
    const int bid = blockIdx.x;          // 8 * MT * 4
    const int p   = bid & 7;
    const int q   = bid >> 3;
    const int mt  = q >> 2;
    const int seg = q & 3;
    const int w   = threadIdx.x >> 6;
    const int l   = threadIdx.x & 63;

    char* tiles = (char*)xt + (size_t)((p * MT + mt) * 32) * 16384;
    const int ktl = l >> 3;              // within-round tile 0..7
    const int e8  = (l & 7) * 8;         // byte offset within 64B row

#pragma unroll 2
    for (int i = 0; i < 16; ++i) {
        const int r = seg * 64 + w * 16 + i;
        const float* src = x + (size_t)(m_base + mt * 256 + r) * ROWSTRIDE + p * FIN;
        char* rowdst = tiles + r * 64 + e8;
#pragma unroll
        for (int rnd = 0; rnd < 4; ++rnd) {
            fx4 v = *(const fx4*)(src + rnd * 256 + l * 4);   // 1 KB contiguous/wave
            BCvt4 u;
            u.b[0] = (__bf16)v[0]; u.b[1] = (__bf16)v[1];
            u.b[2] = (__bf16)v[2]; u.b[3] = (__bf16)v[3];
            *(sv4*)(rowdst + (size_t)(rnd * 8 + ktl) * 16384) = u.s;
        }
    }
}

// ---------------------------------------------------------------------------
// 256x128 GEMM, BK=32, 256 thr (4 waves 2x2, wave 128x64), tri-buffered,
// pure global_load_lds, 6 loads/tile, vmcnt(6) + 1 barrier per K-tile.
// 72 KB LDS -> 2 independent blocks/CU.
// ---------------------------------------------------------------------------
#define STR2(x) #x
#define MEMF asm volatile("" ::: "memory")

#define GLA(kt, As) do {                                                       \
    const char* s_ = apanel + (size_t)(kt) * 16384 + tid * 16;                 \
    char* d_ = (As) + tid * 16;                                                \
    _Pragma("unroll")                                                          \
    for (int c_ = 0; c_ < 4; ++c_)                                             \
        __builtin_amdgcn_global_load_lds(                                      \
            (const __attribute__((address_space(1))) void*)(s_ + c_ * 4096),   \
            (__attribute__((address_space(3))) void*)(d_ + c_ * 4096), 16, 0, 0); \
    MEMF;                                                                      \
} while (0)

#define GLB(kt, Bs) do {                                                       \
    const char* s_ = bpan + (size_t)(kt) * 8192 + tid * 16;                    \
    char* d_ = (Bs) + tid * 16;                                                \
    _Pragma("unroll")                                                          \
    for (int c_ = 0; c_ < 2; ++c_)                                             \
        __builtin_amdgcn_global_load_lds(                                      \
            (const __attribute__((address_space(1))) void*)(s_ + c_ * 4096),   \
            (__attribute__((address_space(3))) void*)(d_ + c_ * 4096), 16, 0, 0); \
    MEMF;                                                                      \
} while (0)

// A frags: 8 x ds_read_b128, rows wm*128 + fi*16 + (lane&15), 64B rows
#define RDA(Ac) do {                                                           \
    _Pragma("unroll")                                                          \
    for (int fi_ = 0; fi_ < 8; ++fi_) {                                        \
        const int row_ = wm * 128 + fi_ * 16 + (lane & 15);                    \
        af[fi_] = *(const sv8*)((Ac) + row_ * 64 + (lane >> 4) * 16);          \
    }                                                                          \
} while (0)

// B frags: 4 reads, rows wn*64 + fj*16 + (lane&15)
#define RDB(Bc) do {                                                           \
    _Pragma("unroll")                                                          \
    for (int fj_ = 0; fj_ < 4; ++fj_) {                                        \
        const int row_ = wn * 64 + fj_ * 16 + (lane & 15);                     \
        bf[fj_] = *(const sv8*)((Bc) + row_ * 64 + (lane >> 4) * 16);          \
    }                                                                          \
} while (0)

#define MFMAS do {                                                             \
    __builtin_amdgcn_s_setprio(1);                                             \
    _Pragma("unroll")                                                          \
    for (int fi_ = 0; fi_ < 8; ++fi_)                                          \
        _Pragma("unroll")                                                      \
        for (int fj_ = 0; fj_ < 4; ++fj_)                                      \
            acc[fi_][fj_] = __builtin_amdgcn_mfma_f32_16x16x32_bf16(           \
                af[fi_], bf[fj_], acc[fi_][fj_], 0, 0, 0);                     \
    __builtin_amdgcn_s_setprio(0);                                             \
} while (0)

// Ledger: entry = 6 outstanding (tile t+1). Issue 6 (tile t+2) -> 12;
// vmcnt(6) retires t+1's. ENDW: 2 = vmcnt(6), 1 = vmcnt(0), 0 = none.
#define TILE(Ar, Br, As, Bs, skt, STG, ENDW) do {                              \
    if (STG) { GLA(skt, As); GLB(skt, Bs); }                                   \
    RDA(Ar); RDB(Br);                                                          \
    MFMAS;                                                                     \
    if ((ENDW) == 2) {                                                         \
        asm volatile("s_waitcnt vmcnt(6)" ::: "memory");                       \
        __builtin_amdgcn_s_barrier(); MEMF;                                    \
    } else if ((ENDW) == 1) {                                                  \
        asm volatile("s_waitcnt vmcnt(0)" ::: "memory");                       \
        __builtin_amdgcn_s_barrier(); MEMF;                                    \
    }                                                                          \
} while (0)

__global__ __launch_bounds__(256, 2)
void pd_gemm(const unsigned short* __restrict__ xt, const unsigned short* __restrict__ wtb,
             const float* __restrict__ bias, float* __restrict__ out,
             int m_base, int MT) {
    __shared__ __align__(16) char A0[16384];
    __shared__ __align__(16) char A1[16384];
    __shared__ __align__(16) char A2[16384];
    __shared__ __align__(16) char B0[8192];
    __shared__ __align__(16) char B1[8192];
    __shared__ __align__(16) char B2[8192];    // 72 KB -> 2 blocks/CU

    const int tid = threadIdx.x;
    const int lane = tid & 63;
    const int wv = tid >> 6;            // 4 waves: 2(m) x 2(n); wave = 128x64
    const int wm = wv >> 1, wn = wv & 1;

    // p == XCD fastest; nt next (A-panel sharers adjacent); mt last
    const int bid = blockIdx.x;
    const int p   = bid & 7;
    const int nt  = (bid >> 3) & 7;
    const int mt  = bid >> 6;
    const int n0  = nt * 128;

    const char* apanel = (const char*)xt  + (size_t)((p * MT + mt) * 32) * 16384;
    const char* bpan   = (const char*)wtb + (size_t)((p * 8 + nt) * 32) * 8192;

    fx4 acc[8][4];
#pragma unroll
    for (int i = 0; i < 8; ++i)
#pragma unroll
        for (int j = 0; j < 4; ++j) acc[i][j] = (fx4)0.0f;

    sv8 af[8], bf[4];

    // Prologue: tile0 -> {A0,B0}, tile1 -> {A1,B1}; vmcnt(6) keeps tile1 in flight
    GLA(0, A0); GLB(0, B0);
    GLA(1, A1); GLB(1, B1);
    asm volatile("s_waitcnt vmcnt(6)" ::: "memory");
    __builtin_amdgcn_s_barrier();
    MEMF;

    // 32 K-tiles; tile t reads buf t%3, stages t+2 into buf (t+2)%3
#pragma unroll 1
    for (int tg = 0; tg < 10; ++tg) {
        const int t = tg * 3;
        TILE(A0, B0, A2, B2, t + 2, 1, 2);
        TILE(A1, B1, A0, B0, t + 3, 1, 2);
        TILE(A2, B2, A1, B1, t + 4, 1, 2);
    }
    TILE(A0, B0, A1, B1, 0, 0, 1);   // t=30: drain tile31's loads
    TILE(A1, B1, A2, B2, 0, 0, 0);   // t=31

    // Epilogue: C/D map col = lane&15, row = (lane>>4)*4 + j (verified r1-r10)
    const float* bs = bias + p * FOUT;
#pragma unroll
    for (int fj = 0; fj < 4; ++fj) {
        const int col = n0 + wn * 64 + fj * 16 + (lane & 15);
        const float bv = bs[col];
#pragma unroll
        for (int fi = 0; fi < 8; ++fi) {
            const int row = m_base + mt * 256 + wm * 128 + fi * 16 + (lane >> 4) * 4;
            float* o = out + (size_t)row * OROWSTRIDE + p * FOUT + col;
#pragma unroll
            for (int j = 0; j < 4; ++j)
                o[j * OROWSTRIDE] = acc[fi][fj][j] + bv;
        }
    }
}

// Fallback if d_ws too small: correct but slow (fp32 exact).
__global__ __launch_bounds__(256) void pd_naive(const float* __restrict__ x,
                                                const float* __restrict__ w,
                                                const float* __restrict__ bias,
                                                float* __restrict__ out) {
    const long long total = (long long)MROWS * PP * FOUT;
    for (long long idx = blockIdx.x * 256LL + threadIdx.x; idx < total;
         idx += (long long)gridDim.x * 256) {
        const int n = (int)(idx & 1023);
        const int p = (int)((idx >> 10) & 7);
        const long long m = idx >> 13;
        const float* xr = x + m * ROWSTRIDE + p * FIN;
        const float* wc = w + (size_t)p * (FIN*FOUT) + n;
        float s = bias[p * FOUT + n];
        for (int k = 0; k < FIN; ++k) s += xr[k] * wc[(size_t)k * FOUT];
        out[idx] = s;
    }
}

extern "C" void kernel_launch(void* const* d_in, const int* in_sizes, int n_in,
                              void* d_out, int out_size, void* d_ws, size_t ws_size,
                              hipStream_t stream) {
    const float* x    = (const float*)d_in[0];
    const float* w    = (const float*)d_in[1];
    const float* bias = (const float*)d_in[2];
    float* out = (float*)d_out;

    const size_t WT_BYTES = (size_t)PP * FIN * FOUT * 2;          // 16.8 MB
    const size_t XT_FULL  = (size_t)MROWS * PP * FIN * 2;         // 134.2 MB

    int nch = 1;
    while (nch <= 32 && WT_BYTES + XT_FULL / nch > ws_size) nch <<= 1;
    if (nch > 32) {
        pd_naive<<<dim3(2048), dim3(256), 0, stream>>>(x, w, bias, out);
        return;
    }

    unsigned short* wt = (unsigned short*)d_ws;
    unsigned short* xt = (unsigned short*)((char*)d_ws + WT_BYTES);
    const int Mc = MROWS / nch;
    const int MT = Mc / 256;

    wtrans<<<dim3(1024), dim3(256), 0, stream>>>(w, wt);
    for (int c = 0; c < nch; ++c) {
        const int m_base = c * Mc;
        xcvt<<<dim3(8 * MT * 4), dim3(256), 0, stream>>>(x, xt, m_base, MT);
        // 8 p x 8 nt x MT mt
        pd_gemm<<<dim3(64 * MT), dim3(256), 0, stream>>>(xt, wt, bias, out, m_base, MT);
    }
}